// Round 1
// baseline (35.618 us; speedup 1.0000x reference)
//
#include <hip/hip_runtime.h>

#define D_MODEL 1024
#define N_MOD   4
#define EBLK    16              // e-chunks in stage 1
#define ECHUNK  (D_MODEL / EBLK)

// ---------------- Stage 1: partial[m][eb][d] = sum_{e in chunk} Wr[m][e] * Wg[e][d]
__global__ __launch_bounds__(256) void weff_partial_kernel(
    const float* __restrict__ Wg,   // [1024, 1024], Wg[e][d]
    const float* __restrict__ Wr,   // [4, 1024],   Wr[m][e]
    float* __restrict__ partial)    // [4][EBLK][1024]
{
    const int d  = blockIdx.y * 256 + threadIdx.x;   // 0..1023
    const int eb = blockIdx.x;                       // 0..15
    float acc[N_MOD] = {0.f, 0.f, 0.f, 0.f};
    const int e0 = eb * ECHUNK;
    #pragma unroll 4
    for (int e = e0; e < e0 + ECHUNK; ++e) {
        const float wg = Wg[e * D_MODEL + d];        // coalesced across threads
        #pragma unroll
        for (int m = 0; m < N_MOD; ++m)
            acc[m] = fmaf(Wr[m * D_MODEL + e], wg, acc[m]); // uniform (scalar) load
    }
    #pragma unroll
    for (int m = 0; m < N_MOD; ++m)
        partial[(m * EBLK + eb) * D_MODEL + d] = acc[m];
}

// ---------------- Stage 2: Weff[m][d] = sum_eb partial[m][eb][d]
__global__ __launch_bounds__(256) void weff_reduce_kernel(
    const float* __restrict__ partial,  // [4][EBLK][1024]
    float* __restrict__ Weff)           // [4][1024]
{
    const int idx = blockIdx.x * 256 + threadIdx.x;  // 0..4095
    const int m = idx >> 10;
    const int d = idx & (D_MODEL - 1);
    float s = 0.f;
    #pragma unroll
    for (int eb = 0; eb < EBLK; ++eb)
        s += partial[(m * EBLK + eb) * D_MODEL + d];
    Weff[idx] = s;
}

// ---------------- Main: one wave per row.
// logits[m] = <h[row], Weff[m]>; probs = softmax; mask = probs>0.5;
// out[m][row][0:4] = mask ? {.5,.5,0,0} : {1,0,0,0}
__global__ __launch_bounds__(256) void router_main_kernel(
    const float* __restrict__ h,     // [B, 1024]
    const float* __restrict__ Weff,  // [4, 1024]
    float* __restrict__ out,         // [4][B][4]
    int B)
{
    const int lane = threadIdx.x & 63;
    const int wave = threadIdx.x >> 6;

    // Each lane caches its Weff slice in registers: w4[m][c] covers d = 4*(c*64+lane)..+3
    float4 w4[N_MOD][4];
    const float4* __restrict__ W4 = (const float4*)Weff;
    #pragma unroll
    for (int m = 0; m < N_MOD; ++m)
        #pragma unroll
        for (int c = 0; c < 4; ++c)
            w4[m][c] = W4[m * 256 + c * 64 + lane];

    float4* __restrict__ out4 = (float4*)out;        // [4][B] float4s
    const int wavesTotal = gridDim.x * 4;

    for (int row = blockIdx.x * 4 + wave; row < B; row += wavesTotal) {
        const float4* __restrict__ h4 = (const float4*)(h + (size_t)row * D_MODEL);
        float acc[N_MOD] = {0.f, 0.f, 0.f, 0.f};
        #pragma unroll
        for (int c = 0; c < 4; ++c) {
            const float4 v = h4[c * 64 + lane];      // wave covers 4KB contiguous
            #pragma unroll
            for (int m = 0; m < N_MOD; ++m) {
                acc[m] = fmaf(v.x, w4[m][c].x, acc[m]);
                acc[m] = fmaf(v.y, w4[m][c].y, acc[m]);
                acc[m] = fmaf(v.z, w4[m][c].z, acc[m]);
                acc[m] = fmaf(v.w, w4[m][c].w, acc[m]);
            }
        }
        // Butterfly reduce over 64 lanes -> every lane holds all 4 logits.
        #pragma unroll
        for (int off = 32; off; off >>= 1) {
            #pragma unroll
            for (int m = 0; m < N_MOD; ++m)
                acc[m] += __shfl_xor(acc[m], off, 64);
        }
        // prob_m > 0.5  <=>  2*exp(l_m - mx) > sum_j exp(l_j - mx)
        const float mx = fmaxf(fmaxf(acc[0], acc[1]), fmaxf(acc[2], acc[3]));
        float ex[N_MOD];
        float S = 0.f;
        #pragma unroll
        for (int m = 0; m < N_MOD; ++m) { ex[m] = expf(acc[m] - mx); S += ex[m]; }

        if (lane < N_MOD) {
            const bool hi = (2.f * ex[lane] > S);
            const float4 val = hi ? make_float4(0.5f, 0.5f, 0.f, 0.f)
                                  : make_float4(1.f, 0.f, 0.f, 0.f);
            out4[(size_t)lane * B + row] = val;
        }
    }
}

extern "C" void kernel_launch(void* const* d_in, const int* in_sizes, int n_in,
                              void* d_out, int out_size, void* d_ws, size_t ws_size,
                              hipStream_t stream) {
    const float* h  = (const float*)d_in[0];   // [B, 1024]
    const float* Wg = (const float*)d_in[1];   // [1024, 1024]
    const float* Wr = (const float*)d_in[2];   // [4, 1024]
    float* out = (float*)d_out;                // [4][B][4]

    const int B = in_sizes[0] / D_MODEL;       // 32768

    float* Weff    = (float*)d_ws;                         // 4096 floats (16 KB)
    float* partial = (float*)d_ws + N_MOD * D_MODEL;       // 65536 floats (256 KB)

    // Stage 1: 16 e-chunks x 4 d-chunks
    dim3 g1(EBLK, D_MODEL / 256);
    weff_partial_kernel<<<g1, 256, 0, stream>>>(Wg, Wr, partial);

    // Stage 2: 4096 threads
    weff_reduce_kernel<<<(N_MOD * D_MODEL) / 256, 256, 0, stream>>>(partial, Weff);

    // Main: 2048 blocks x 256 threads = 8192 waves, 4 rows each
    router_main_kernel<<<2048, 256, 0, stream>>>(h, Weff, out, B);
}